// Round 20
// baseline (54.724 us; speedup 1.0000x reference)
//
#include <hip/hip_runtime.h>

typedef float  f32x4  __attribute__((ext_vector_type(4)));
typedef float  f32x4a __attribute__((ext_vector_type(4), aligned(4)));
typedef __bf16 bf16x8 __attribute__((ext_vector_type(8)));
typedef short  short8 __attribute__((ext_vector_type(8)));

#define F      65
#define NTT    17           // 16 D-tiles of 16 cols + 1 S-tile
#define KS3    3            // K padded (65 + bias) -> 96, 3 ksteps of 32
#define RPB    256          // rows per tile (8 waves x 32 rows)
#define NCHUNK (NTT*KS3*64) // 3264 16B chunks (52224 B)
#define GRID   512          // persistent blocks: 2/CU x 256 CU
#define NITER  2            // row-tiles per block (1024 total)
#define NEGL2E -1.4426950408889634f

__device__ __forceinline__ float fast_sigmoid(float x) {
  float e = __builtin_amdgcn_exp2f(NEGL2E * x);
  return __builtin_amdgcn_rcpf(1.0f + e);
}
// acc pre-scaled by -log2e: sigmoid = rcp(1 + exp2(acc))
__device__ __forceinline__ float sig_prescaled(float a) {
  return __builtin_amdgcn_rcpf(1.0f + __builtin_amdgcn_exp2f(a));
}
template<int CTRL>
__device__ __forceinline__ float dpp_mov(float v) {
  return __builtin_bit_cast(float,
    __builtin_amdgcn_update_dpp(0, __builtin_bit_cast(int, v), CTRL, 0xF, 0xF, true));
}
__device__ __forceinline__ float reduce16(float v) {
  v += dpp_mov<0xB1>(v);                   // xor1
  v += dpp_mov<0x4E>(v);                   // xor2
  v += dpp_mov<0x141>(v);                  // xor4 (row_half_mirror)
  v += dpp_mov<0x140>(v);                  // xor8 (row_mirror)
  return v;
}

// ---- prepass: fragment-ordered bf16 W blob; D-part pre-scaled by -log2e ----
// chunk = (t*3+s)*64 + lane ; lane holds 8 bf16 of B:
//   col n = 16*t + (lane&15), k = 32*s + 8*(lane>>4) + j   (k==65 is bias row)
__global__ void prep_w(const float* __restrict__ W_S, const float* __restrict__ b_S,
                       const float* __restrict__ W_D, const float* __restrict__ b_D,
                       unsigned short* __restrict__ wsb) {
  int b = blockIdx.x;              // 0..50 = t*3+s
  int t = b / 3, s = b % 3;
  int l = threadIdx.x;
  int c = l & 15, q = l >> 4;
  short8 out;
#pragma unroll
  for (int j = 0; j < 8; ++j) {
    int k = 32 * s + 8 * q + j;
    float v = 0.0f;
    if (t < 16) {
      int n = 16 * t + c;
      if (k < F)       v = NEGL2E * W_D[n * F + k];
      else if (k == F) v = NEGL2E * b_D[n];
    } else if (c < 8) {
      if (k < F)       v = W_S[c * F + k];
      else if (k == F) v = b_S[c];
    }
    unsigned int u = __builtin_bit_cast(unsigned int, v);
    u += 0x7FFFu + ((u >> 16) & 1u);
    out[j] = (short)(u >> 16);
  }
  reinterpret_cast<short8*>(wsb)[b * 64 + l] = out;
}

// ---- main: persistent blocks, blob staged once, phi pipelined across tiles -
__launch_bounds__(512, 4)   // 4 waves/EU -> reg cap 128; LDS -> 2 blocks/CU
__global__ void mpuf_main(const float* __restrict__ phi,
                          const unsigned short* __restrict__ wsb,
                          float* __restrict__ out_ans,
                          float* __restrict__ out_rel) {
  __shared__ short8 ldsB[NCHUNK];          // 52224 B : W blob (staged ONCE)
  __shared__ float  soutv[RPB][12];        // 12288 B (wave-private rows)
  __shared__ float  mtT[16][260];          // 16640 B : Mt[t][row] transposed
  // total 81152 B -> 2 blocks/CU; rel bounce overlays mtT (barrier-ordered)

  const int tid  = threadIdx.x;
  const int wave = tid >> 6;
  const int l    = tid & 63;
  const int c    = l & 15;
  const int q    = l >> 4;
  const int wrow = wave * 32;
  const int R0b  = wrow + q * 4;
  float* relbuf = &mtT[0][0];

  // ---- prologue: phi loads for tile 0 + one-time blob staging --------------
  const float* prow0 = phi + (size_t)(blockIdx.x * RPB + wrow + c) * F;
  const float* prow1 = prow0 + (size_t)16 * F;
  f32x4a f40[4], f41[4];
#pragma unroll
  for (int s = 0; s < 2; ++s) {
    f40[2 * s]     = *reinterpret_cast<const f32x4a*>(prow0 + 32 * s + 8 * q);
    f40[2 * s + 1] = *reinterpret_cast<const f32x4a*>(prow0 + 32 * s + 8 * q + 4);
    f41[2 * s]     = *reinterpret_cast<const f32x4a*>(prow1 + 32 * s + 8 * q);
    f41[2 * s + 1] = *reinterpret_cast<const f32x4a*>(prow1 + 32 * s + 8 * q + 4);
  }
  float a640 = prow0[64];
  float a641 = prow1[64];

  const short8* wsv = reinterpret_cast<const short8*>(wsb);
#pragma unroll
  for (int i = 0; i < 7; ++i) {
    int idx = tid + i * 512;
    if (idx < NCHUNK) ldsB[idx] = wsv[idx];
  }
  __syncthreads();                         // blob ready (once)

#pragma unroll 1
  for (int it = 0; it < NITER; ++it) {
    const int tl   = blockIdx.x + it * GRID;
    const int brow = tl * RPB;
    if (it) __syncthreads();               // prev D-loop mtT reads done

    // A -> bf16 fragments (consumes f4; regs then reused for next-tile loads)
    bf16x8 af0[3], af1[3];
#pragma unroll
    for (int s = 0; s < 2; ++s) {
      bf16x8 v0, v1;
#pragma unroll
      for (int j = 0; j < 4; ++j) {
        v0[j]     = (__bf16)f40[s * 2][j];
        v0[j + 4] = (__bf16)f40[s * 2 + 1][j];
        v1[j]     = (__bf16)f41[s * 2][j];
        v1[j + 4] = (__bf16)f41[s * 2 + 1][j];
      }
      af0[s] = v0; af1[s] = v1;
    }
    {
      bf16x8 v0 = {}, v1 = {};
      if (q == 0) {
        v0[0] = (__bf16)a640; v0[1] = (__bf16)1.0f; // k=64 + bias row
        v1[0] = (__bf16)a641; v1[1] = (__bf16)1.0f;
      }
      af0[2] = v0; af1[2] = v1;
    }

    // issue NEXT tile's phi loads now: latency hides under S+D of this tile
    if (it + 1 < NITER) {
      const float* nrow0 = phi + (size_t)((tl + GRID) * RPB + wrow + c) * F;
      const float* nrow1 = nrow0 + (size_t)16 * F;
#pragma unroll
      for (int s = 0; s < 2; ++s) {
        f40[2 * s]     = *reinterpret_cast<const f32x4a*>(nrow0 + 32 * s + 8 * q);
        f40[2 * s + 1] = *reinterpret_cast<const f32x4a*>(nrow0 + 32 * s + 8 * q + 4);
        f41[2 * s]     = *reinterpret_cast<const f32x4a*>(nrow1 + 32 * s + 8 * q);
        f41[2 * s + 1] = *reinterpret_cast<const f32x4a*>(nrow1 + 32 * s + 8 * q + 4);
      }
      a640 = nrow0[64];
      a641 = nrow1[64];
    }

    // ---- S tile (t=16, unscaled): Sdelta with bias folded -------------------
    f32x4 aS0 = {}, aS1 = {};
#pragma unroll
    for (int s = 0; s < KS3; ++s) {
      bf16x8 b = __builtin_bit_cast(bf16x8, ldsB[(16 * KS3 + s) * 64 + l]);
      aS0 = __builtin_amdgcn_mfma_f32_16x16x32_bf16(af0[s], b, aS0, 0, 0, 0);
      aS1 = __builtin_amdgcn_mfma_f32_16x16x32_bf16(af1[s], b, aS1, 0, 0, 0);
    }

    // prefetch D-tile 0 while S epilogue runs
    short8 bnxt[3];
#pragma unroll
    for (int s = 0; s < 3; ++s) bnxt[s] = ldsB[s * 64 + l];

    // C layout 16x16: col = lane&15, row = (lane>>4)*4 + r
    if (c < 8) {
#pragma unroll
      for (int r = 0; r < 4; ++r) {
        const int R0 = R0b + r, R1 = R0 + 16;
        relbuf[R0 * 8 + c] = fabsf(aS0[r]);
        relbuf[R1 * 8 + c] = fabsf(aS1[r]);
        soutv[R0][c] = fast_sigmoid(aS0[r]);
        soutv[R1][c] = fast_sigmoid(aS1[r]);
      }
    }
    // rel bounce read is same-wave -> lgkm-ordered.

    // ---- coalesced out_rel store: 1 KB contiguous per wave -----------------
    {
      const int row = l >> 1, half = l & 1;
      f32x4 v = *reinterpret_cast<const f32x4*>(&relbuf[(wrow + row) * 8 + half * 4]);
      *reinterpret_cast<f32x4*>(
          &out_rel[(size_t)(brow + wrow + row) * 8 + half * 4]) = v;
    }

    __syncthreads();                       // rel reads done before mtT writes

    // ---- per-row records: Ml in regs, Mt into transposed mtT ---------------
    float Ml0[4], Ml1[4];
#pragma unroll
    for (int rr = 0; rr < 8; ++rr) {
      const int R = wrow + (rr & 4) * 4 + q * 4 + (rr & 3);
      f32x4 s03 = *reinterpret_cast<const f32x4*>(&soutv[R][0]);
      f32x4 s47 = *reinterpret_cast<const f32x4*>(&soutv[R][4]);
      float m = 0.99999f;
      m *= (c & 1) ? s03[0] : 1.0f - s03[0];
      m *= (c & 2) ? s03[1] : 1.0f - s03[1];
      m *= (c & 4) ? s03[2] : 1.0f - s03[2];
      m *= (c & 8) ? s03[3] : 1.0f - s03[3];
      if (rr < 4) Ml0[rr & 3] = m; else Ml1[rr & 3] = m;
      float mt = (c & 1) ? s47[0] : 1.0f - s47[0];
      mt *= (c & 2) ? s47[1] : 1.0f - s47[1];
      mt *= (c & 4) ? s47[2] : 1.0f - s47[2];
      mt *= (c & 8) ? s47[3] : 1.0f - s47[3];
      mtT[c][R] = mt;
    }

    float ans0[4] = {0, 0, 0, 0}, ans1[4] = {0, 0, 0, 0};

    // ---- D loop: B from LDS, 1-ahead prefetch ------------------------------
#pragma unroll 1
    for (int t = 0; t < 16; ++t) {
      short8 bt[3];
#pragma unroll
      for (int s = 0; s < 3; ++s) bt[s] = bnxt[s];
      const int tn = (t < 15) ? t + 1 : 15;
#pragma unroll
      for (int s = 0; s < 3; ++s)
        bnxt[s] = ldsB[(tn * KS3 + s) * 64 + l];
      f32x4 w0 = *reinterpret_cast<const f32x4*>(&mtT[t][R0b]);
      f32x4 w1 = *reinterpret_cast<const f32x4*>(&mtT[t][R0b + 16]);
      f32x4 A0 = {}, A1 = {};
#pragma unroll
      for (int s = 0; s < KS3; ++s) {
        bf16x8 b = __builtin_bit_cast(bf16x8, bt[s]);
        A0 = __builtin_amdgcn_mfma_f32_16x16x32_bf16(af0[s], b, A0, 0, 0, 0);
        A1 = __builtin_amdgcn_mfma_f32_16x16x32_bf16(af1[s], b, A1, 0, 0, 0);
      }
#pragma unroll
      for (int r = 0; r < 4; ++r) {
        ans0[r] = fmaf(sig_prescaled(A0[r]), w0[r], ans0[r]);
        ans1[r] = fmaf(sig_prescaled(A1[r]), w1[r], ans1[r]);
      }
    }

    // ---- apply Ml, 16-lane DPP reduce, vectorized store --------------------
    f32x4 o0, o1;
#pragma unroll
    for (int r = 0; r < 4; ++r) {
      o0[r] = reduce16(Ml0[r] * ans0[r]);
      o1[r] = reduce16(Ml1[r] * ans1[r]);
    }
    if (c == 0) {
      *reinterpret_cast<f32x4*>(&out_ans[brow + wrow + q * 4])      = o0;
      *reinterpret_cast<f32x4*>(&out_ans[brow + wrow + 16 + q * 4]) = o1;
    }
  }
}

extern "C" void kernel_launch(void* const* d_in, const int* in_sizes, int n_in,
                              void* d_out, int out_size, void* d_ws, size_t ws_size,
                              hipStream_t stream) {
  const float* phi = (const float*)d_in[0];
  const float* W_S = (const float*)d_in[1];
  const float* b_S = (const float*)d_in[2];
  const float* W_D = (const float*)d_in[3];
  const float* b_D = (const float*)d_in[4];
  const int rows = in_sizes[0] / F;        // 262144
  (void)rows;                              // geometry fixed: GRID*NITER*RPB
  unsigned short* wsb = (unsigned short*)d_ws;   // 52224 B used
  float* out_ans = (float*)d_out;
  float* out_rel = out_ans + rows;
  hipLaunchKernelGGL(prep_w, dim3(NTT * KS3), dim3(64), 0, stream,
                     W_S, b_S, W_D, b_D, wsb);
  hipLaunchKernelGGL(mpuf_main, dim3(GRID), dim3(512), 0, stream,
                     phi, wsb, out_ans, out_rel);
}

// Round 21
// 37.505 us; speedup vs baseline: 1.4591x; 1.4591x over previous
//
#include <hip/hip_runtime.h>

typedef float  f32x4  __attribute__((ext_vector_type(4)));
typedef float  f32x4a __attribute__((ext_vector_type(4), aligned(4)));
typedef __bf16 bf16x8 __attribute__((ext_vector_type(8)));
typedef short  short8 __attribute__((ext_vector_type(8)));

#define F      65
#define NTT    17           // 16 D-tiles of 16 cols + 1 S-tile
#define KS3    3            // K padded (65 + bias) -> 96, 3 ksteps of 32
#define RPB    256          // rows per block (8 waves x 32 rows)
#define NCHUNK (NTT*KS3*64) // 3264 16B chunks (52224 B)
#define NEGL2E -1.4426950408889634f

__device__ __forceinline__ float fast_sigmoid(float x) {
  float e = __builtin_amdgcn_exp2f(NEGL2E * x);
  return __builtin_amdgcn_rcpf(1.0f + e);
}
// acc pre-scaled by -log2e: sigmoid = rcp(1 + exp2(acc))
__device__ __forceinline__ float sig_prescaled(float a) {
  return __builtin_amdgcn_rcpf(1.0f + __builtin_amdgcn_exp2f(a));
}
template<int CTRL>
__device__ __forceinline__ float dpp_mov(float v) {
  return __builtin_bit_cast(float,
    __builtin_amdgcn_update_dpp(0, __builtin_bit_cast(int, v), CTRL, 0xF, 0xF, true));
}
__device__ __forceinline__ float reduce16(float v) {
  v += dpp_mov<0xB1>(v);                   // xor1
  v += dpp_mov<0x4E>(v);                   // xor2
  v += dpp_mov<0x141>(v);                  // xor4 (row_half_mirror)
  v += dpp_mov<0x140>(v);                  // xor8 (row_mirror)
  return v;
}

// ---- prepass: fragment-ordered bf16 W blob; D-part pre-scaled by -log2e ----
// chunk = (t*3+s)*64 + lane ; lane holds 8 bf16 of B:
//   col n = 16*t + (lane&15), k = 32*s + 8*(lane>>4) + j   (k==65 is bias row)
__global__ void prep_w(const float* __restrict__ W_S, const float* __restrict__ b_S,
                       const float* __restrict__ W_D, const float* __restrict__ b_D,
                       unsigned short* __restrict__ wsb) {
  int b = blockIdx.x;              // 0..50 = t*3+s
  int t = b / 3, s = b % 3;
  int l = threadIdx.x;
  int c = l & 15, q = l >> 4;
  short8 out;
#pragma unroll
  for (int j = 0; j < 8; ++j) {
    int k = 32 * s + 8 * q + j;
    float v = 0.0f;
    if (t < 16) {
      int n = 16 * t + c;
      if (k < F)       v = NEGL2E * W_D[n * F + k];
      else if (k == F) v = NEGL2E * b_D[n];
    } else if (c < 8) {
      if (k < F)       v = W_S[c * F + k];
      else if (k == F) v = b_S[c];
    }
    unsigned int u = __builtin_bit_cast(unsigned int, v);
    u += 0x7FFFu + ((u >> 16) & 1u);
    out[j] = (short)(u >> 16);
  }
  reinterpret_cast<short8*>(wsb)[b * 64 + l] = out;
}

// ---- main: R19 + PER-WAVE staggered D-tile start (convoy breaker) ---------
__launch_bounds__(512, 4)   // 4 waves/EU -> reg cap 128; LDS -> 2 blocks/CU
__global__ void mpuf_main(const float* __restrict__ phi,
                          const unsigned short* __restrict__ wsb,
                          float* __restrict__ out_ans,
                          float* __restrict__ out_rel) {
  __shared__ short8 ldsB[NCHUNK];          // 52224 B : W blob
  __shared__ float  soutv[RPB][12];        // 12288 B (stride 12: b128 rows)
  __shared__ float  mtT[16][260];          // 16640 B : Mt[t][row] transposed
  // total 81152 B -> 2 blocks/CU; rel bounce overlays mtT (barrier-ordered)

  const int tid  = threadIdx.x;
  const int wave = tid >> 6;
  const int l    = tid & 63;
  const int c    = l & 15;                 // col-in-tile / row-in-A-fragment
  const int q    = l >> 4;                 // k-group / C-row quad
  const int wrow = wave * 32;
  const int R0b  = wrow + q * 4;           // this lane's C-row quad base
  const int brow = blockIdx.x * RPB;
  // per-WAVE stagger: 8 waves spread over all 16 tiles; block parity shifts
  const int tstart = (2 * wave + (blockIdx.x & 1)) & 15;

  float* relbuf = &mtT[0][0];              // 2048 floats, then reused as mtT

  const float* prow0 = phi + (size_t)(brow + wrow + c) * F;
  const float* prow1 = prow0 + (size_t)16 * F;

  // phi loads first (HBM latency hides under staging)
  f32x4a f40[4], f41[4];
#pragma unroll
  for (int s = 0; s < 2; ++s) {
    f40[2 * s]     = *reinterpret_cast<const f32x4a*>(prow0 + 32 * s + 8 * q);
    f40[2 * s + 1] = *reinterpret_cast<const f32x4a*>(prow0 + 32 * s + 8 * q + 4);
    f41[2 * s]     = *reinterpret_cast<const f32x4a*>(prow1 + 32 * s + 8 * q);
    f41[2 * s + 1] = *reinterpret_cast<const f32x4a*>(prow1 + 32 * s + 8 * q + 4);
  }
  const float a640 = prow0[64];
  const float a641 = prow1[64];

  // stage W blob -> LDS (coalesced, 7 rounds of 512 threads)
  const short8* wsv = reinterpret_cast<const short8*>(wsb);
#pragma unroll
  for (int i = 0; i < 7; ++i) {
    int idx = tid + i * 512;
    if (idx < NCHUNK) ldsB[idx] = wsv[idx];
  }

  // A -> bf16 fragments
  bf16x8 af0[3], af1[3];
#pragma unroll
  for (int s = 0; s < 2; ++s) {
    bf16x8 v0, v1;
#pragma unroll
    for (int j = 0; j < 4; ++j) {
      v0[j]     = (__bf16)f40[s * 2][j];
      v0[j + 4] = (__bf16)f40[s * 2 + 1][j];
      v1[j]     = (__bf16)f41[s * 2][j];
      v1[j + 4] = (__bf16)f41[s * 2 + 1][j];
    }
    af0[s] = v0; af1[s] = v1;
  }
  {
    bf16x8 v0 = {}, v1 = {};
    if (q == 0) {
      v0[0] = (__bf16)a640; v0[1] = (__bf16)1.0f;   // k=64 + bias row
      v1[0] = (__bf16)a641; v1[1] = (__bf16)1.0f;
    }
    af0[2] = v0; af1[2] = v1;
  }

  __syncthreads();                         // blob ready

  // ---- S tile (t=16, unscaled): Sdelta with bias folded --------------------
  f32x4 aS0 = {}, aS1 = {};
#pragma unroll
  for (int s = 0; s < KS3; ++s) {
    bf16x8 b = __builtin_bit_cast(bf16x8, ldsB[(16 * KS3 + s) * 64 + l]);
    aS0 = __builtin_amdgcn_mfma_f32_16x16x32_bf16(af0[s], b, aS0, 0, 0, 0);
    aS1 = __builtin_amdgcn_mfma_f32_16x16x32_bf16(af1[s], b, aS1, 0, 0, 0);
  }

  // prefetch this wave's FIRST staggered D-tile while S epilogue runs
  short8 bnxt[3];
#pragma unroll
  for (int s = 0; s < 3; ++s) bnxt[s] = ldsB[(tstart * KS3 + s) * 64 + l];

  // C layout 16x16: col = lane&15, row = (lane>>4)*4 + r
  if (c < 8) {
#pragma unroll
    for (int r = 0; r < 4; ++r) {
      const int R0 = R0b + r, R1 = R0 + 16;
      relbuf[R0 * 8 + c] = fabsf(aS0[r]);
      relbuf[R1 * 8 + c] = fabsf(aS1[r]);
      soutv[R0][c] = fast_sigmoid(aS0[r]);
      soutv[R1][c] = fast_sigmoid(aS1[r]);
    }
  }
  // rel bounce read is same-wave (rows wrow..wrow+31) -> lgkm-ordered.

  // ---- coalesced out_rel store: 1 KB contiguous per wave -------------------
  {
    const int row = l >> 1, half = l & 1;
    f32x4 v = *reinterpret_cast<const f32x4*>(&relbuf[(wrow + row) * 8 + half * 4]);
    *reinterpret_cast<f32x4*>(
        &out_rel[(size_t)(brow + wrow + row) * 8 + half * 4]) = v;
  }

  __syncthreads();                         // all rel reads done before mtT writes

  // ---- per-row records: Ml in regs, Mt into transposed mtT -----------------
  float Ml0[4], Ml1[4];
#pragma unroll
  for (int rr = 0; rr < 8; ++rr) {
    const int R = wrow + (rr & 4) * 4 + q * 4 + (rr & 3);
    f32x4 s03 = *reinterpret_cast<const f32x4*>(&soutv[R][0]);
    f32x4 s47 = *reinterpret_cast<const f32x4*>(&soutv[R][4]);
    float m = 0.99999f;
    m *= (c & 1) ? s03[0] : 1.0f - s03[0];
    m *= (c & 2) ? s03[1] : 1.0f - s03[1];
    m *= (c & 4) ? s03[2] : 1.0f - s03[2];
    m *= (c & 8) ? s03[3] : 1.0f - s03[3];
    if (rr < 4) Ml0[rr & 3] = m; else Ml1[rr & 3] = m;
    float mt = (c & 1) ? s47[0] : 1.0f - s47[0];
    mt *= (c & 2) ? s47[1] : 1.0f - s47[1];
    mt *= (c & 4) ? s47[2] : 1.0f - s47[2];
    mt *= (c & 8) ? s47[3] : 1.0f - s47[3];
    mtT[c][R] = mt;
  }

  float ans0[4] = {0, 0, 0, 0}, ans1[4] = {0, 0, 0, 0};

  // ---- D loop: per-wave staggered tile order (tiles independent) -----------
#pragma unroll 1
  for (int tt = 0; tt < 16; ++tt) {
    const int t  = (tt + tstart) & 15;
    const int tn = (tt + 1 + tstart) & 15;
    short8 bt[3];
#pragma unroll
    for (int s = 0; s < 3; ++s) bt[s] = bnxt[s];       // current tile
#pragma unroll
    for (int s = 0; s < 3; ++s)                        // issue next reads NOW
      bnxt[s] = ldsB[(tn * KS3 + s) * 64 + l];
    // coef reads issued before MFMAs (hidden under them)
    f32x4 w0 = *reinterpret_cast<const f32x4*>(&mtT[t][R0b]);
    f32x4 w1 = *reinterpret_cast<const f32x4*>(&mtT[t][R0b + 16]);
    f32x4 A0 = {}, A1 = {};
#pragma unroll
    for (int s = 0; s < KS3; ++s) {
      bf16x8 b = __builtin_bit_cast(bf16x8, bt[s]);
      A0 = __builtin_amdgcn_mfma_f32_16x16x32_bf16(af0[s], b, A0, 0, 0, 0);
      A1 = __builtin_amdgcn_mfma_f32_16x16x32_bf16(af1[s], b, A1, 0, 0, 0);
    }
#pragma unroll
    for (int r = 0; r < 4; ++r) {
      ans0[r] = fmaf(sig_prescaled(A0[r]), w0[r], ans0[r]);
      ans1[r] = fmaf(sig_prescaled(A1[r]), w1[r], ans1[r]);
    }
  }

  // ---- apply Ml, 16-lane DPP reduce, vectorized store ----------------------
  f32x4 o0, o1;
#pragma unroll
  for (int r = 0; r < 4; ++r) {
    o0[r] = reduce16(Ml0[r] * ans0[r]);
    o1[r] = reduce16(Ml1[r] * ans1[r]);
  }
  if (c == 0) {
    *reinterpret_cast<f32x4*>(&out_ans[brow + wrow + q * 4])      = o0;
    *reinterpret_cast<f32x4*>(&out_ans[brow + wrow + 16 + q * 4]) = o1;
  }
}

extern "C" void kernel_launch(void* const* d_in, const int* in_sizes, int n_in,
                              void* d_out, int out_size, void* d_ws, size_t ws_size,
                              hipStream_t stream) {
  const float* phi = (const float*)d_in[0];
  const float* W_S = (const float*)d_in[1];
  const float* b_S = (const float*)d_in[2];
  const float* W_D = (const float*)d_in[3];
  const float* b_D = (const float*)d_in[4];
  const int rows = in_sizes[0] / F;        // 262144
  unsigned short* wsb = (unsigned short*)d_ws;   // 52224 B used
  float* out_ans = (float*)d_out;
  float* out_rel = out_ans + rows;
  hipLaunchKernelGGL(prep_w, dim3(NTT * KS3), dim3(64), 0, stream,
                     W_S, b_S, W_D, b_D, wsb);
  hipLaunchKernelGGL(mpuf_main, dim3(rows / RPB), dim3(512), 0, stream,
                     phi, wsb, out_ans, out_rel);
}